// Round 2
// baseline (571.568 us; speedup 1.0000x reference)
//
#include <hip/hip_runtime.h>
#include <stdint.h>

#define B_ 16
#define K_ 2048
#define D_ 512
#define INNER_ 1024
#define M_ (B_*K_)      // 32768 rows
#define KW_ 5
#define EPS_ 1e-5f
#define NC_ 8
#define CL_ (K_/NC_)    // 256 per chunk

typedef __attribute__((ext_vector_type(8))) short short8;
typedef __attribute__((ext_vector_type(4))) float f32x4;

typedef const __attribute__((address_space(1))) unsigned int* gas_u32;
typedef __attribute__((address_space(3))) unsigned int* las_u32;

static __device__ __forceinline__ float bf2f(unsigned short u) {
    unsigned int v = ((unsigned int)u) << 16;
    return __builtin_bit_cast(float, v);
}
static __device__ __forceinline__ unsigned short f2bf(float f) {
    unsigned int x = __builtin_bit_cast(unsigned int, f);
    unsigned int r = (x + 0x7FFFu + ((x >> 16) & 1u)) >> 16;
    return (unsigned short)r;
}

// ---------------- weight fp32 -> bf16 conversion ----------------
__global__ __launch_bounds__(256) void k_wconv(const float* __restrict__ Wa,
                                               const float* __restrict__ Wb,
                                               const float* __restrict__ Wout,
                                               unsigned short* __restrict__ Wcat,
                                               unsigned short* __restrict__ WoutB) {
    const int NW = INNER_ * D_;  // 524288
    int idx = blockIdx.x * 256 + threadIdx.x;
    if (idx < NW)            Wcat[idx]       = f2bf(Wa[idx]);
    else if (idx < 2 * NW)   Wcat[idx]       = f2bf(Wb[idx - NW]);
    else                     WoutB[idx-2*NW] = f2bf(Wout[idx - 2*NW]);
}

// ---------------- RMSNorm: one wave per row of 512 ----------------
__global__ __launch_bounds__(256) void k_rmsnorm(const float* __restrict__ x,
                                                 const float* __restrict__ w,
                                                 unsigned short* __restrict__ h) {
    int row  = blockIdx.x * 4 + (threadIdx.x >> 6);
    int lane = threadIdx.x & 63;
    const float4* xr = (const float4*)(x + (size_t)row * D_);
    float4 v0 = xr[lane];
    float4 v1 = xr[64 + lane];
    float ss = v0.x*v0.x + v0.y*v0.y + v0.z*v0.z + v0.w*v0.w
             + v1.x*v1.x + v1.y*v1.y + v1.z*v1.z + v1.w*v1.w;
    #pragma unroll
    for (int off = 32; off; off >>= 1) ss += __shfl_xor(ss, off, 64);
    float r = rsqrtf(ss * (1.0f / D_) + EPS_);
    const float4* wv = (const float4*)w;
    float4 w0 = wv[lane], w1 = wv[64 + lane];
    ushort4 o0, o1;
    o0.x = f2bf(v0.x * r * w0.x); o0.y = f2bf(v0.y * r * w0.y);
    o0.z = f2bf(v0.z * r * w0.z); o0.w = f2bf(v0.w * r * w0.w);
    o1.x = f2bf(v1.x * r * w1.x); o1.y = f2bf(v1.y * r * w1.y);
    o1.z = f2bf(v1.z * r * w1.z); o1.w = f2bf(v1.w * r * w1.w);
    ushort4* hr = (ushort4*)(h + (size_t)row * D_);
    hr[lane]      = o0;
    hr[64 + lane] = o1;
}

// ---------------- bf16 MFMA GEMM, C = A * B^T (both row-major [*, Kd]) -------
// 128x128 tile, BK=64, 4 waves (2x2), each wave 64x64 = 4x4 frags of 16x16.
// LDS linear dest for global_load_lds; XOR swizzle byte^=((row&7)<<4) applied
// via pre-swizzled global source + swizzled ds_read (both-sides rule).
// EPI==0: store bf16 C [M,Nld].  EPI==1: store fp32 out = Xadd + acc.
template<int EPI>
__global__ __launch_bounds__(256) void k_gemm_bt(
    const unsigned short* __restrict__ A,
    const unsigned short* __restrict__ Bw,
    void* __restrict__ Cv,
    const float* __restrict__ Xadd,
    int Kd, int Nld)
{
    __shared__ __align__(16) unsigned short lA[128 * 64];
    __shared__ __align__(16) unsigned short lB[128 * 64];
    const int tid  = threadIdx.x;
    const int w    = tid >> 6, lane = tid & 63;
    const int wr   = w >> 1,   wc   = w & 1;
    const int m0   = blockIdx.x * 128, n0 = blockIdx.y * 128;

    // staging map: chunk j covers rows [j*32, j*32+32); row = j*32 + (tid>>3)
    const int srow = tid >> 3;                       // 0..31
    const int scol = ((tid & 7) ^ (srow & 7)) << 3;  // swizzled source col (elems)

    f32x4 acc[4][4];
    #pragma unroll
    for (int i = 0; i < 4; ++i)
        #pragma unroll
        for (int j = 0; j < 4; ++j) acc[i][j] = (f32x4){0.f, 0.f, 0.f, 0.f};

    const int lrow = lane & 15;
    const int kb16 = (lane >> 4) << 4;  // byte offset within 128B row

    for (int kt = 0; kt < Kd; kt += 64) {
        #pragma unroll
        for (int j = 0; j < 4; ++j) {
            const unsigned short* gA = A + (size_t)(m0 + j*32 + srow) * Kd + kt + scol;
            __builtin_amdgcn_global_load_lds((gas_u32)gA, (las_u32)(lA + j*2048 + w*512), 16, 0, 0);
            const unsigned short* gB = Bw + (size_t)(n0 + j*32 + srow) * Kd + kt + scol;
            __builtin_amdgcn_global_load_lds((gas_u32)gB, (las_u32)(lB + j*2048 + w*512), 16, 0, 0);
        }
        __syncthreads();
        #pragma unroll
        for (int kk = 0; kk < 2; ++kk) {
            short8 af[4], bfr[4];
            #pragma unroll
            for (int i = 0; i < 4; ++i) {
                int rowa  = wr*64 + i*16 + lrow;
                int addra = rowa*128 + ((kk*64 + kb16) ^ ((rowa & 7) << 4));
                af[i]  = *(const short8*)((const char*)lA + addra);
                int rowb  = wc*64 + i*16 + lrow;
                int addrb = rowb*128 + ((kk*64 + kb16) ^ ((rowb & 7) << 4));
                bfr[i] = *(const short8*)((const char*)lB + addrb);
            }
            #pragma unroll
            for (int i = 0; i < 4; ++i)
                #pragma unroll
                for (int j = 0; j < 4; ++j)
                    acc[i][j] = __builtin_amdgcn_mfma_f32_16x16x32_bf16(af[i], bfr[j], acc[i][j], 0, 0, 0);
        }
        __syncthreads();
    }

    // epilogue: D layout col = lane&15, row = (lane>>4)*4 + r
    #pragma unroll
    for (int i = 0; i < 4; ++i) {
        int mrow = m0 + wr*64 + i*16 + ((lane >> 4) << 2);
        #pragma unroll
        for (int j = 0; j < 4; ++j) {
            int ncol = n0 + wc*64 + j*16 + (lane & 15);
            f32x4 v = acc[i][j];
            #pragma unroll
            for (int r = 0; r < 4; ++r) {
                size_t off = (size_t)(mrow + r) * Nld + ncol;
                if (EPI == 0) ((unsigned short*)Cv)[off] = f2bf(v[r]);
                else          ((float*)Cv)[off] = Xadd[off] + v[r];
            }
        }
    }
}

// ---------------- conv5 + SiLU + chunked selective scan ----------------
// ab: bf16 [M, 2048] (cols 0..1023 = a, 1024..2047 = b)
// pass 0: compute per-chunk end state sEnd[b, c, i]
// pass 1: prefix-correct via A^CL, recompute, emit g bf16 [M, 1024]
__global__ __launch_bounds__(256) void k_scan(
    const unsigned short* __restrict__ ab,
    const float* __restrict__ conv_w, const float* __restrict__ conv_b,
    const float* __restrict__ alpha,  const float* __restrict__ beta,
    const float* __restrict__ gamma,  const float* __restrict__ delta,
    float* __restrict__ sEnd, unsigned short* __restrict__ g, int pass)
{
    const int i = blockIdx.x * 256 + threadIdx.x;  // channel 0..1023
    const int c = blockIdx.y;                      // chunk
    const int b = blockIdx.z;                      // batch

    const float w0 = conv_w[i*KW_+0], w1 = conv_w[i*KW_+1], w2 = conv_w[i*KW_+2],
                w3 = conv_w[i*KW_+3], w4 = conv_w[i*KW_+4];
    const float bias = conv_b[i];
    const float Aa  = 1.f / (1.f + expf(-alpha[i]));
    const float bet = beta[i], gam = gamma[i], del = delta[i];

    const int k0 = c * CL_;
    const size_t rowbase = (size_t)b * K_;

    #define LDA(k) (((k) >= 0 && (k) < K_) ? bf2f(ab[(rowbase + (k)) * 2048 + i]) : 0.f)

    float am2 = LDA(k0 - 2), am1 = LDA(k0 - 1), a0v = LDA(k0), ap1 = LDA(k0 + 1);
    float s = 0.f;
    if (pass == 1) {
        float Ap = Aa;
        #pragma unroll
        for (int t = 0; t < 8; ++t) Ap = Ap * Ap;   // A^256
        float sin_ = 0.f;
        for (int cp = 0; cp < c; ++cp)
            sin_ = sin_ * Ap + sEnd[((size_t)(b * NC_ + cp)) * INNER_ + i];
        s = sin_;
    }

    #pragma unroll 4
    for (int kk = 0; kk < CL_; ++kk) {
        int k = k0 + kk;
        float ap2 = LDA(k + 2);
        float v = w0*am2 + w1*am1 + w2*a0v + w3*ap1 + w4*ap2 + bias;
        float u = v / (1.f + expf(-v));            // SiLU
        s = Aa * s + bet * u;
        if (pass == 1) {
            float bv = bf2f(ab[(rowbase + k) * 2048 + INNER_ + i]);
            float gv = (gam * s + del * u) * bv;
            g[(rowbase + k) * INNER_ + i] = f2bf(gv);
        }
        am2 = am1; am1 = a0v; a0v = ap1; ap1 = ap2;
    }
    if (pass == 0) sEnd[((size_t)(b * NC_ + c)) * INNER_ + i] = s;
    #undef LDA
}

// ---------------- launch ----------------
extern "C" void kernel_launch(void* const* d_in, const int* in_sizes, int n_in,
                              void* d_out, int out_size, void* d_ws, size_t ws_size,
                              hipStream_t stream) {
    const float* x      = (const float*)d_in[0];
    const float* norm_w = (const float*)d_in[1];
    const float* Wa     = (const float*)d_in[2];
    const float* Wb     = (const float*)d_in[3];
    const float* conv_w = (const float*)d_in[4];
    const float* conv_b = (const float*)d_in[5];
    const float* alpha  = (const float*)d_in[6];
    const float* beta   = (const float*)d_in[7];
    const float* gamma  = (const float*)d_in[8];
    const float* delta  = (const float*)d_in[9];
    const float* Wout   = (const float*)d_in[10];
    float* out = (float*)d_out;

    char* ws = (char*)d_ws;
    unsigned short* h    = (unsigned short*)ws; ws += (size_t)M_ * D_ * 2;        // 32 MB
    unsigned short* Wcat = (unsigned short*)ws; ws += (size_t)2048 * 512 * 2;     // 2 MB
    unsigned short* WoB  = (unsigned short*)ws; ws += (size_t)512 * 1024 * 2;     // 1 MB
    unsigned short* abb  = (unsigned short*)ws; ws += (size_t)M_ * 2048 * 2;      // 128 MB
    unsigned short* g    = (unsigned short*)ws; ws += (size_t)M_ * 1024 * 2;      // 64 MB
    float* sEnd          = (float*)ws;          ws += (size_t)B_ * NC_ * INNER_ * 4;

    k_wconv  <<<6144, 256, 0, stream>>>(Wa, Wb, Wout, Wcat, WoB);
    k_rmsnorm<<<M_ / 4, 256, 0, stream>>>(x, norm_w, h);
    // a|b = h @ [Wa;Wb]^T : M=32768, K=512, N=2048
    k_gemm_bt<0><<<dim3(M_ / 128, 2048 / 128), 256, 0, stream>>>(h, Wcat, abb, nullptr, 512, 2048);
    // chunked scan, two passes (exact)
    k_scan<<<dim3(INNER_ / 256, NC_, B_), 256, 0, stream>>>(abb, conv_w, conv_b, alpha, beta, gamma, delta, sEnd, g, 0);
    k_scan<<<dim3(INNER_ / 256, NC_, B_), 256, 0, stream>>>(abb, conv_w, conv_b, alpha, beta, gamma, delta, sEnd, g, 1);
    // out = x + g @ Wout^T : M=32768, K=1024, N=512
    k_gemm_bt<1><<<dim3(M_ / 128, 512 / 128), 256, 0, stream>>>(g, WoB, out, x, 1024, 512);
}

// Round 3
// 389.778 us; speedup vs baseline: 1.4664x; 1.4664x over previous
//
#include <hip/hip_runtime.h>
#include <stdint.h>

#define B_ 16
#define K_ 2048
#define D_ 512
#define INNER_ 1024
#define M_ (B_*K_)      // 32768 rows
#define KW_ 5
#define EPS_ 1e-5f
#define NC_ 64
#define CL_ (K_/NC_)    // 32 per chunk

typedef __attribute__((ext_vector_type(8))) short short8;
typedef __attribute__((ext_vector_type(4))) float f32x4;
typedef __attribute__((ext_vector_type(8))) float f32x8;

typedef const __attribute__((address_space(1))) unsigned int* gas_u32;
typedef __attribute__((address_space(3))) unsigned int* las_u32;

static __device__ __forceinline__ float bf2f(unsigned short u) {
    unsigned int v = ((unsigned int)u) << 16;
    return __builtin_bit_cast(float, v);
}
static __device__ __forceinline__ unsigned short f2bf(float f) {
    unsigned int x = __builtin_bit_cast(unsigned int, f);
    unsigned int r = (x + 0x7FFFu + ((x >> 16) & 1u)) >> 16;
    return (unsigned short)r;
}
static __device__ __forceinline__ f32x8 cvt8(short8 v) {
    f32x8 f;
    #pragma unroll
    for (int j = 0; j < 8; ++j) f[j] = bf2f((unsigned short)v[j]);
    return f;
}

// ---------------- weight fp32 -> bf16 conversion ----------------
__global__ __launch_bounds__(256) void k_wconv(const float* __restrict__ Wa,
                                               const float* __restrict__ Wb,
                                               const float* __restrict__ Wout,
                                               unsigned short* __restrict__ Wcat,
                                               unsigned short* __restrict__ WoutB) {
    const int NW = INNER_ * D_;  // 524288
    int idx = blockIdx.x * 256 + threadIdx.x;
    if (idx < NW)            Wcat[idx]       = f2bf(Wa[idx]);
    else if (idx < 2 * NW)   Wcat[idx]       = f2bf(Wb[idx - NW]);
    else                     WoutB[idx-2*NW] = f2bf(Wout[idx - 2*NW]);
}

// ---------------- RMSNorm: one wave per row of 512 ----------------
__global__ __launch_bounds__(256) void k_rmsnorm(const float* __restrict__ x,
                                                 const float* __restrict__ w,
                                                 unsigned short* __restrict__ h) {
    int row  = blockIdx.x * 4 + (threadIdx.x >> 6);
    int lane = threadIdx.x & 63;
    const float4* xr = (const float4*)(x + (size_t)row * D_);
    float4 v0 = xr[lane];
    float4 v1 = xr[64 + lane];
    float ss = v0.x*v0.x + v0.y*v0.y + v0.z*v0.z + v0.w*v0.w
             + v1.x*v1.x + v1.y*v1.y + v1.z*v1.z + v1.w*v1.w;
    #pragma unroll
    for (int off = 32; off; off >>= 1) ss += __shfl_xor(ss, off, 64);
    float r = rsqrtf(ss * (1.0f / D_) + EPS_);
    const float4* wv = (const float4*)w;
    float4 w0 = wv[lane], w1 = wv[64 + lane];
    ushort4 o0, o1;
    o0.x = f2bf(v0.x * r * w0.x); o0.y = f2bf(v0.y * r * w0.y);
    o0.z = f2bf(v0.z * r * w0.z); o0.w = f2bf(v0.w * r * w0.w);
    o1.x = f2bf(v1.x * r * w1.x); o1.y = f2bf(v1.y * r * w1.y);
    o1.z = f2bf(v1.z * r * w1.z); o1.w = f2bf(v1.w * r * w1.w);
    ushort4* hr = (ushort4*)(h + (size_t)row * D_);
    hr[lane]      = o0;
    hr[64 + lane] = o1;
}

// ---------------- bf16 MFMA GEMM, C = A * B^T (both row-major [*, Kd]) -------
template<int EPI>
__global__ __launch_bounds__(256) void k_gemm_bt(
    const unsigned short* __restrict__ A,
    const unsigned short* __restrict__ Bw,
    void* __restrict__ Cv,
    const float* __restrict__ Xadd,
    int Kd, int Nld)
{
    __shared__ __align__(16) unsigned short lA[128 * 64];
    __shared__ __align__(16) unsigned short lB[128 * 64];
    const int tid  = threadIdx.x;
    const int w    = tid >> 6, lane = tid & 63;
    const int wr   = w >> 1,   wc   = w & 1;
    const int m0   = blockIdx.x * 128, n0 = blockIdx.y * 128;

    const int srow = tid >> 3;                       // 0..31
    const int scol = ((tid & 7) ^ (srow & 7)) << 3;  // swizzled source col (elems)

    f32x4 acc[4][4];
    #pragma unroll
    for (int i = 0; i < 4; ++i)
        #pragma unroll
        for (int j = 0; j < 4; ++j) acc[i][j] = (f32x4){0.f, 0.f, 0.f, 0.f};

    const int lrow = lane & 15;
    const int kb16 = (lane >> 4) << 4;  // byte offset within 128B row

    for (int kt = 0; kt < Kd; kt += 64) {
        #pragma unroll
        for (int j = 0; j < 4; ++j) {
            const unsigned short* gA = A + (size_t)(m0 + j*32 + srow) * Kd + kt + scol;
            __builtin_amdgcn_global_load_lds((gas_u32)gA, (las_u32)(lA + j*2048 + w*512), 16, 0, 0);
            const unsigned short* gB = Bw + (size_t)(n0 + j*32 + srow) * Kd + kt + scol;
            __builtin_amdgcn_global_load_lds((gas_u32)gB, (las_u32)(lB + j*2048 + w*512), 16, 0, 0);
        }
        __syncthreads();
        #pragma unroll
        for (int kk = 0; kk < 2; ++kk) {
            short8 af[4], bfr[4];
            #pragma unroll
            for (int i = 0; i < 4; ++i) {
                int rowa  = wr*64 + i*16 + lrow;
                int addra = rowa*128 + ((kk*64 + kb16) ^ ((rowa & 7) << 4));
                af[i]  = *(const short8*)((const char*)lA + addra);
                int rowb  = wc*64 + i*16 + lrow;
                int addrb = rowb*128 + ((kk*64 + kb16) ^ ((rowb & 7) << 4));
                bfr[i] = *(const short8*)((const char*)lB + addrb);
            }
            #pragma unroll
            for (int i = 0; i < 4; ++i)
                #pragma unroll
                for (int j = 0; j < 4; ++j)
                    acc[i][j] = __builtin_amdgcn_mfma_f32_16x16x32_bf16(af[i], bfr[j], acc[i][j], 0, 0, 0);
        }
        __syncthreads();
    }

    #pragma unroll
    for (int i = 0; i < 4; ++i) {
        int mrow = m0 + wr*64 + i*16 + ((lane >> 4) << 2);
        #pragma unroll
        for (int j = 0; j < 4; ++j) {
            int ncol = n0 + wc*64 + j*16 + (lane & 15);
            f32x4 v = acc[i][j];
            #pragma unroll
            for (int r = 0; r < 4; ++r) {
                size_t off = (size_t)(mrow + r) * Nld + ncol;
                if (EPI == 0) ((unsigned short*)Cv)[off] = f2bf(v[r]);
                else          ((float*)Cv)[off] = Xadd[off] + v[r];
            }
        }
    }
}

// ---------------- prefix: per (b,channel), chain chunk-end states ----------
// sPre[b][c][i] = state entering chunk c (A^CL-weighted sum of prior ends)
__global__ __launch_bounds__(256) void k_prefix(const float* __restrict__ alpha,
                                                const float* __restrict__ sEnd,
                                                float* __restrict__ sPre) {
    int idx = blockIdx.x * 256 + threadIdx.x;   // 0..16383
    int b = idx >> 10, i = idx & 1023;
    float Aa = 1.f / (1.f + __expf(-alpha[i]));
    float Ap = Aa;
    #pragma unroll
    for (int t = 0; t < 5; ++t) Ap = Ap * Ap;   // Aa^32 (CL=32)
    float s = 0.f;
    for (int c = 0; c < NC_; ++c) {
        size_t off = ((size_t)(b * NC_ + c)) * INNER_ + i;
        sPre[off] = s;
        s = s * Ap + sEnd[off];
    }
}

// ---------------- conv5 + SiLU + chunked selective scan (vectorized x8) -----
// ab: bf16 [M, 2048] (cols 0..1023 = a, 1024..2047 = b)
// PASS 0: per-chunk end state -> sEnd.  PASS 1: start from sPre, emit g bf16.
// Each thread owns 8 channels (short8 = 16B loads/stores). 128 thr/(b,c).
template<int PASS>
__global__ __launch_bounds__(256) void k_scan(
    const unsigned short* __restrict__ ab,
    const float* __restrict__ conv_w, const float* __restrict__ conv_b,
    const float* __restrict__ alpha,  const float* __restrict__ beta,
    const float* __restrict__ gamma,  const float* __restrict__ delta,
    float* __restrict__ sEnd, const float* __restrict__ sPre,
    unsigned short* __restrict__ g)
{
    const int tid = threadIdx.x;
    const int c   = blockIdx.x * 2 + (tid >> 7);   // chunk 0..63 (wave-uniform)
    const int b   = blockIdx.y;
    const int ch  = (tid & 127) * 8;               // channel base 0..1016

    // per-channel params as f32x8
    f32x8 w0, w1, w2, w3, w4, bias, Aa, bet, gam, del;
    #pragma unroll
    for (int j = 0; j < 8; ++j) {
        int i = ch + j;
        w0[j] = conv_w[i*KW_+0]; w1[j] = conv_w[i*KW_+1]; w2[j] = conv_w[i*KW_+2];
        w3[j] = conv_w[i*KW_+3]; w4[j] = conv_w[i*KW_+4];
        bias[j] = conv_b[i];
        Aa[j]  = 1.f / (1.f + __expf(-alpha[i]));
        bet[j] = beta[i];
        if (PASS == 1) { gam[j] = gamma[i]; del[j] = delta[i]; }
    }

    const int k0 = c * CL_;
    const size_t rowbase = (size_t)b * K_;

    // guarded vector load of a-row k (wave-uniform guard)
    #define LDV(k) (((unsigned)(k) < (unsigned)K_) \
        ? cvt8(*(const short8*)(ab + (rowbase + (k)) * 2048 + ch)) \
        : (f32x8){0.f,0.f,0.f,0.f,0.f,0.f,0.f,0.f})

    f32x8 am2 = LDV(k0 - 2), am1 = LDV(k0 - 1), a0v = LDV(k0), ap1 = LDV(k0 + 1);

    f32x8 s;
    if (PASS == 1) {
        s = *(const f32x8*)(sPre + ((size_t)(b * NC_ + c)) * INNER_ + ch);
    } else {
        #pragma unroll
        for (int j = 0; j < 8; ++j) s[j] = 0.f;
    }

    #pragma unroll 2
    for (int kk = 0; kk < CL_; ++kk) {
        int k = k0 + kk;
        f32x8 ap2 = LDV(k + 2);
        f32x8 v = w0*am2 + w1*am1 + w2*a0v + w3*ap1 + w4*ap2 + bias;
        f32x8 u;
        #pragma unroll
        for (int j = 0; j < 8; ++j) u[j] = v[j] / (1.f + __expf(-v[j]));
        s = Aa * s + bet * u;
        if (PASS == 1) {
            f32x8 bv = cvt8(*(const short8*)(ab + (rowbase + k) * 2048 + INNER_ + ch));
            f32x8 gv = (gam * s + del * u) * bv;
            short8 o;
            #pragma unroll
            for (int j = 0; j < 8; ++j) o[j] = (short)f2bf(gv[j]);
            *(short8*)(g + (rowbase + k) * INNER_ + ch) = o;
        }
        am2 = am1; am1 = a0v; a0v = ap1; ap1 = ap2;
    }
    if (PASS == 0)
        *(f32x8*)(sEnd + ((size_t)(b * NC_ + c)) * INNER_ + ch) = s;
    #undef LDV
}

// ---------------- launch ----------------
extern "C" void kernel_launch(void* const* d_in, const int* in_sizes, int n_in,
                              void* d_out, int out_size, void* d_ws, size_t ws_size,
                              hipStream_t stream) {
    const float* x      = (const float*)d_in[0];
    const float* norm_w = (const float*)d_in[1];
    const float* Wa     = (const float*)d_in[2];
    const float* Wb     = (const float*)d_in[3];
    const float* conv_w = (const float*)d_in[4];
    const float* conv_b = (const float*)d_in[5];
    const float* alpha  = (const float*)d_in[6];
    const float* beta   = (const float*)d_in[7];
    const float* gamma  = (const float*)d_in[8];
    const float* delta  = (const float*)d_in[9];
    const float* Wout   = (const float*)d_in[10];
    float* out = (float*)d_out;

    char* ws = (char*)d_ws;
    unsigned short* h    = (unsigned short*)ws; ws += (size_t)M_ * D_ * 2;        // 32 MB
    unsigned short* Wcat = (unsigned short*)ws; ws += (size_t)2048 * 512 * 2;     // 2 MB
    unsigned short* WoB  = (unsigned short*)ws; ws += (size_t)512 * 1024 * 2;     // 1 MB
    unsigned short* abb  = (unsigned short*)ws; ws += (size_t)M_ * 2048 * 2;      // 128 MB
    unsigned short* g    = (unsigned short*)ws; ws += (size_t)M_ * 1024 * 2;      // 64 MB
    float* sEnd          = (float*)ws;          ws += (size_t)B_ * NC_ * INNER_ * 4; // 4 MB
    float* sPre          = (float*)ws;          ws += (size_t)B_ * NC_ * INNER_ * 4; // 4 MB

    k_wconv  <<<6144, 256, 0, stream>>>(Wa, Wb, Wout, Wcat, WoB);
    k_rmsnorm<<<M_ / 4, 256, 0, stream>>>(x, norm_w, h);
    // a|b = h @ [Wa;Wb]^T : M=32768, K=512, N=2048
    k_gemm_bt<0><<<dim3(M_ / 128, 2048 / 128), 256, 0, stream>>>(h, Wcat, abb, nullptr, 512, 2048);
    // chunked scan: pass0 (chunk ends) -> prefix chain -> pass1 (emit g)
    k_scan<0><<<dim3(NC_ / 2, B_), 256, 0, stream>>>(abb, conv_w, conv_b, alpha, beta, gamma, delta, sEnd, nullptr, g);
    k_prefix<<<64, 256, 0, stream>>>(alpha, sEnd, sPre);
    k_scan<1><<<dim3(NC_ / 2, B_), 256, 0, stream>>>(abb, conv_w, conv_b, alpha, beta, gamma, delta, sEnd, sPre, g);
    // out = x + g @ Wout^T : M=32768, K=1024, N=512
    k_gemm_bt<1><<<dim3(M_ / 128, 512 / 128), 256, 0, stream>>>(g, WoB, out, x, 1024, 512);
}

// Round 5
// 366.335 us; speedup vs baseline: 1.5602x; 1.0640x over previous
//
#include <hip/hip_runtime.h>
#include <stdint.h>

#define B_ 16
#define K_ 2048
#define D_ 512
#define INNER_ 1024
#define M_ (B_*K_)      // 32768 rows
#define KW_ 5
#define EPS_ 1e-5f
#define NC_ 64
#define CL_ (K_/NC_)    // 32 per chunk

typedef __attribute__((ext_vector_type(8))) short short8;
typedef __attribute__((ext_vector_type(4))) float f32x4;
typedef __attribute__((ext_vector_type(8))) float f32x8;

typedef const __attribute__((address_space(1))) unsigned int* gas_u32;
typedef __attribute__((address_space(3))) unsigned int* las_u32;

static __device__ __forceinline__ float bf2f(unsigned short u) {
    unsigned int v = ((unsigned int)u) << 16;
    return __builtin_bit_cast(float, v);
}
static __device__ __forceinline__ unsigned short f2bf(float f) {
    unsigned int x = __builtin_bit_cast(unsigned int, f);
    unsigned int r = (x + 0x7FFFu + ((x >> 16) & 1u)) >> 16;
    return (unsigned short)r;
}
static __device__ __forceinline__ f32x8 cvt8(short8 v) {
    f32x8 f;
    #pragma unroll
    for (int j = 0; j < 8; ++j) f[j] = bf2f((unsigned short)v[j]);
    return f;
}

// ---------------- weight fp32 -> bf16 conversion ----------------
__global__ __launch_bounds__(256) void k_wconv(const float* __restrict__ Wa,
                                               const float* __restrict__ Wb,
                                               const float* __restrict__ Wout,
                                               unsigned short* __restrict__ Wcat,
                                               unsigned short* __restrict__ WoutB) {
    const int NW = INNER_ * D_;  // 524288
    int idx = blockIdx.x * 256 + threadIdx.x;
    if (idx < NW)            Wcat[idx]       = f2bf(Wa[idx]);
    else if (idx < 2 * NW)   Wcat[idx]       = f2bf(Wb[idx - NW]);
    else                     WoutB[idx-2*NW] = f2bf(Wout[idx - 2*NW]);
}

// ---------------- RMSNorm: one wave per row of 512 ----------------
__global__ __launch_bounds__(256) void k_rmsnorm(const float* __restrict__ x,
                                                 const float* __restrict__ w,
                                                 unsigned short* __restrict__ h) {
    int row  = blockIdx.x * 4 + (threadIdx.x >> 6);
    int lane = threadIdx.x & 63;
    const float4* xr = (const float4*)(x + (size_t)row * D_);
    float4 v0 = xr[lane];
    float4 v1 = xr[64 + lane];
    float ss = v0.x*v0.x + v0.y*v0.y + v0.z*v0.z + v0.w*v0.w
             + v1.x*v1.x + v1.y*v1.y + v1.z*v1.z + v1.w*v1.w;
    #pragma unroll
    for (int off = 32; off; off >>= 1) ss += __shfl_xor(ss, off, 64);
    float r = rsqrtf(ss * (1.0f / D_) + EPS_);
    const float4* wv = (const float4*)w;
    float4 w0 = wv[lane], w1 = wv[64 + lane];
    ushort4 o0, o1;
    o0.x = f2bf(v0.x * r * w0.x); o0.y = f2bf(v0.y * r * w0.y);
    o0.z = f2bf(v0.z * r * w0.z); o0.w = f2bf(v0.w * r * w0.w);
    o1.x = f2bf(v1.x * r * w1.x); o1.y = f2bf(v1.y * r * w1.y);
    o1.z = f2bf(v1.z * r * w1.z); o1.w = f2bf(v1.w * r * w1.w);
    ushort4* hr = (ushort4*)(h + (size_t)row * D_);
    hr[lane]      = o0;
    hr[64 + lane] = o1;
}

// ---------------- 256x256 bf16 MFMA GEMM, C = A * B^T, counted-vmcnt pipe ----
// 8 waves (2M x 4N), per-wave 128x64 out = acc[8][4]. BK=64, 2 LDS dbuf.
// Raw s_barrier (no compiler vmcnt(0) drain); steady-state s_waitcnt vmcnt(8)
// keeps next K-tile's 8 global_load_lds in flight across barriers (T3/T4).
// XOR swizzle byte^=((row&7)<<4) via pre-swizzled global src + swizzled read.
template<int EPI>
__global__ __launch_bounds__(512) void k_gemm256(
    const unsigned short* __restrict__ A,
    const unsigned short* __restrict__ Bw,
    void* __restrict__ Cv,
    const float* __restrict__ Xadd,
    int Kd, int Nld)
{
    __shared__ __align__(16) unsigned short lA[2][256 * 64];
    __shared__ __align__(16) unsigned short lB[2][256 * 64];
    const int tid  = threadIdx.x;
    const int w    = tid >> 6, lane = tid & 63;
    const int wr   = w >> 2,   wc   = w & 3;

    // XCD-aware bijective swizzle of the flattened tile id (nwg % 8 == 0 here)
    const int nwg = gridDim.x * gridDim.y;
    const int fid = blockIdx.y * gridDim.x + blockIdx.x;
    const int swz = (fid & 7) * (nwg >> 3) + (fid >> 3);
    const int m0  = (swz % gridDim.x) * 256;
    const int n0  = (swz / gridDim.x) * 256;

    // staging map: per chunk j (64 rows), wave w fills rows [j*64+w*8, +8)
    const int srow = w * 8 + (lane >> 3);             // + j*64 per chunk
    const int scol = ((lane & 7) ^ (lane >> 3)) << 3; // pre-swizzled source col
    const int NT   = Kd >> 6;

    auto stage = [&](int t, int buf) {
        const int kt = t << 6;
        const unsigned short* ga = A  + (size_t)(m0 + srow) * Kd + kt + scol;
        const unsigned short* gb = Bw + (size_t)(n0 + srow) * Kd + kt + scol;
        #pragma unroll
        for (int j = 0; j < 4; ++j) {
            __builtin_amdgcn_global_load_lds((gas_u32)(ga + (size_t)j * 64 * Kd),
                                             (las_u32)(&lA[buf][(j * 64 + w * 8) * 64]), 16, 0, 0);
            __builtin_amdgcn_global_load_lds((gas_u32)(gb + (size_t)j * 64 * Kd),
                                             (las_u32)(&lB[buf][(j * 64 + w * 8) * 64]), 16, 0, 0);
        }
    };

    f32x4 acc[8][4];
    #pragma unroll
    for (int m = 0; m < 8; ++m)
        #pragma unroll
        for (int n = 0; n < 4; ++n) acc[m][n] = (f32x4){0.f, 0.f, 0.f, 0.f};

    const int lrow = lane & 15;
    const int hb   = (lane >> 4) << 4;   // 16B slot within 128B row
    const int xr   = (lrow & 7) << 4;    // read-side swizzle

    stage(0, 0);
    stage(1, 1);

    for (int t = 0; t < NT; ++t) {
        const int buf = t & 1;
        if (t + 1 < NT) asm volatile("s_waitcnt vmcnt(8)" ::: "memory");
        else            asm volatile("s_waitcnt vmcnt(0)" ::: "memory");
        __builtin_amdgcn_s_barrier();

        const char* pa = (const char*)lA[buf];
        const char* pb = (const char*)lB[buf];

        short8 a0[8], b0[4];
        #pragma unroll
        for (int m = 0; m < 8; ++m)
            a0[m] = *(const short8*)(pa + (wr*128 + m*16 + lrow) * 128 + (hb ^ xr));
        #pragma unroll
        for (int n = 0; n < 4; ++n)
            b0[n] = *(const short8*)(pb + (wc*64 + n*16 + lrow) * 128 + (hb ^ xr));

        __builtin_amdgcn_s_setprio(1);
        #pragma unroll
        for (int m = 0; m < 8; ++m)
            #pragma unroll
            for (int n = 0; n < 4; ++n)
                acc[m][n] = __builtin_amdgcn_mfma_f32_16x16x32_bf16(a0[m], b0[n], acc[m][n], 0, 0, 0);
        __builtin_amdgcn_s_setprio(0);

        short8 a1[8], b1[4];
        #pragma unroll
        for (int m = 0; m < 8; ++m)
            a1[m] = *(const short8*)(pa + (wr*128 + m*16 + lrow) * 128 + ((64 + hb) ^ xr));
        #pragma unroll
        for (int n = 0; n < 4; ++n)
            b1[n] = *(const short8*)(pb + (wc*64 + n*16 + lrow) * 128 + ((64 + hb) ^ xr));

        asm volatile("s_waitcnt lgkmcnt(0)" ::: "memory");   // all reads of buf done
        __builtin_amdgcn_s_barrier();                        // ...across all waves
        if (t + 2 < NT) stage(t + 2, buf);                   // refill while MFMA runs

        __builtin_amdgcn_s_setprio(1);
        #pragma unroll
        for (int m = 0; m < 8; ++m)
            #pragma unroll
            for (int n = 0; n < 4; ++n)
                acc[m][n] = __builtin_amdgcn_mfma_f32_16x16x32_bf16(a1[m], b1[n], acc[m][n], 0, 0, 0);
        __builtin_amdgcn_s_setprio(0);
    }

    // epilogue: D layout col = lane&15, row = (lane>>4)*4 + r
    #pragma unroll
    for (int m = 0; m < 8; ++m) {
        int mrow = m0 + wr*128 + m*16 + ((lane >> 4) << 2);
        #pragma unroll
        for (int n = 0; n < 4; ++n) {
            int ncol = n0 + wc*64 + n*16 + (lane & 15);
            f32x4 v = acc[m][n];
            #pragma unroll
            for (int r = 0; r < 4; ++r) {
                size_t off = (size_t)(mrow + r) * Nld + ncol;
                if (EPI == 0) ((unsigned short*)Cv)[off] = f2bf(v[r]);
                else          ((float*)Cv)[off] = Xadd[off] + v[r];
            }
        }
    }
}

// ---------------- prefix: per (b,channel), chain chunk-end states ----------
__global__ __launch_bounds__(256) void k_prefix(const float* __restrict__ alpha,
                                                const float* __restrict__ sEnd,
                                                float* __restrict__ sPre) {
    int idx = blockIdx.x * 256 + threadIdx.x;   // 0..16383
    int b = idx >> 10, i = idx & 1023;
    float Aa = 1.f / (1.f + __expf(-alpha[i]));
    float Ap = Aa;
    #pragma unroll
    for (int t = 0; t < 5; ++t) Ap = Ap * Ap;   // Aa^32 (CL=32)
    float s = 0.f;
    for (int c = 0; c < NC_; ++c) {
        size_t off = ((size_t)(b * NC_ + c)) * INNER_ + i;
        sPre[off] = s;
        s = s * Ap + sEnd[off];
    }
}

// ---------------- conv5 + SiLU + chunked selective scan (vectorized x8) -----
template<int PASS>
__global__ __launch_bounds__(256) void k_scan(
    const unsigned short* __restrict__ ab,
    const float* __restrict__ conv_w, const float* __restrict__ conv_b,
    const float* __restrict__ alpha,  const float* __restrict__ beta,
    const float* __restrict__ gamma,  const float* __restrict__ delta,
    float* __restrict__ sEnd, const float* __restrict__ sPre,
    unsigned short* __restrict__ g)
{
    const int tid = threadIdx.x;
    const int c   = blockIdx.x * 2 + (tid >> 7);   // chunk 0..63 (wave-uniform)
    const int b   = blockIdx.y;
    const int ch  = (tid & 127) * 8;               // channel base 0..1016

    f32x8 w0, w1, w2, w3, w4, bias, Aa, bet, gam, del;
    #pragma unroll
    for (int j = 0; j < 8; ++j) {
        int i = ch + j;
        w0[j] = conv_w[i*KW_+0]; w1[j] = conv_w[i*KW_+1]; w2[j] = conv_w[i*KW_+2];
        w3[j] = conv_w[i*KW_+3]; w4[j] = conv_w[i*KW_+4];
        bias[j] = conv_b[i];
        Aa[j]  = 1.f / (1.f + __expf(-alpha[i]));
        bet[j] = beta[i];
        if (PASS == 1) { gam[j] = gamma[i]; del[j] = delta[i]; }
    }

    const int k0 = c * CL_;
    const size_t rowbase = (size_t)b * K_;

    #define LDV(k) (((unsigned)(k) < (unsigned)K_) \
        ? cvt8(*(const short8*)(ab + (rowbase + (k)) * 2048 + ch)) \
        : (f32x8){0.f,0.f,0.f,0.f,0.f,0.f,0.f,0.f})

    f32x8 am2 = LDV(k0 - 2), am1 = LDV(k0 - 1), a0v = LDV(k0), ap1 = LDV(k0 + 1);

    f32x8 s;
    if (PASS == 1) {
        s = *(const f32x8*)(sPre + ((size_t)(b * NC_ + c)) * INNER_ + ch);
    } else {
        #pragma unroll
        for (int j = 0; j < 8; ++j) s[j] = 0.f;
    }

    #pragma unroll 2
    for (int kk = 0; kk < CL_; ++kk) {
        int k = k0 + kk;
        f32x8 ap2 = LDV(k + 2);
        f32x8 v = w0*am2 + w1*am1 + w2*a0v + w3*ap1 + w4*ap2 + bias;
        f32x8 u;
        #pragma unroll
        for (int j = 0; j < 8; ++j) u[j] = v[j] / (1.f + __expf(-v[j]));
        s = Aa * s + bet * u;
        if (PASS == 1) {
            f32x8 bv = cvt8(*(const short8*)(ab + (rowbase + k) * 2048 + INNER_ + ch));
            f32x8 gv = (gam * s + del * u) * bv;
            short8 o;
            #pragma unroll
            for (int j = 0; j < 8; ++j) o[j] = (short)f2bf(gv[j]);
            *(short8*)(g + (rowbase + k) * INNER_ + ch) = o;
        }
        am2 = am1; am1 = a0v; a0v = ap1; ap1 = ap2;
    }
    if (PASS == 0)
        *(f32x8*)(sEnd + ((size_t)(b * NC_ + c)) * INNER_ + ch) = s;
    #undef LDV
}

// ---------------- launch ----------------
extern "C" void kernel_launch(void* const* d_in, const int* in_sizes, int n_in,
                              void* d_out, int out_size, void* d_ws, size_t ws_size,
                              hipStream_t stream) {
    const float* x      = (const float*)d_in[0];
    const float* norm_w = (const float*)d_in[1];
    const float* Wa     = (const float*)d_in[2];
    const float* Wb     = (const float*)d_in[3];
    const float* conv_w = (const float*)d_in[4];
    const float* conv_b = (const float*)d_in[5];
    const float* alpha  = (const float*)d_in[6];
    const float* beta   = (const float*)d_in[7];
    const float* gamma  = (const float*)d_in[8];
    const float* delta  = (const float*)d_in[9];
    const float* Wout   = (const float*)d_in[10];
    float* out = (float*)d_out;

    char* ws = (char*)d_ws;
    unsigned short* h    = (unsigned short*)ws; ws += (size_t)M_ * D_ * 2;        // 32 MB
    unsigned short* Wcat = (unsigned short*)ws; ws += (size_t)2048 * 512 * 2;     // 2 MB
    unsigned short* WoB  = (unsigned short*)ws; ws += (size_t)512 * 1024 * 2;     // 1 MB
    unsigned short* abb  = (unsigned short*)ws; ws += (size_t)M_ * 2048 * 2;      // 128 MB
    unsigned short* g    = (unsigned short*)ws; ws += (size_t)M_ * 1024 * 2;      // 64 MB
    float* sEnd          = (float*)ws;          ws += (size_t)B_ * NC_ * INNER_ * 4; // 4 MB
    float* sPre          = (float*)ws;          ws += (size_t)B_ * NC_ * INNER_ * 4; // 4 MB

    k_wconv  <<<6144, 256, 0, stream>>>(Wa, Wb, Wout, Wcat, WoB);
    k_rmsnorm<<<M_ / 4, 256, 0, stream>>>(x, norm_w, h);
    // a|b = h @ [Wa;Wb]^T : M=32768, K=512, N=2048
    k_gemm256<0><<<dim3(M_ / 256, 2048 / 256), 512, 0, stream>>>(h, Wcat, abb, nullptr, 512, 2048);
    // chunked scan: pass0 (chunk ends) -> prefix chain -> pass1 (emit g)
    k_scan<0><<<dim3(NC_ / 2, B_), 256, 0, stream>>>(abb, conv_w, conv_b, alpha, beta, gamma, delta, sEnd, nullptr, g);
    k_prefix<<<64, 256, 0, stream>>>(alpha, sEnd, sPre);
    k_scan<1><<<dim3(NC_ / 2, B_), 256, 0, stream>>>(abb, conv_w, conv_b, alpha, beta, gamma, delta, sEnd, sPre, g);
    // out = x + g @ Wout^T : M=32768, K=1024, N=512
    k_gemm256<1><<<dim3(M_ / 256, 512 / 256), 512, 0, stream>>>(g, WoB, out, x, 1024, 512);
}

// Round 6
// 358.457 us; speedup vs baseline: 1.5945x; 1.0220x over previous
//
#include <hip/hip_runtime.h>
#include <stdint.h>

#define B_ 16
#define K_ 2048
#define D_ 512
#define INNER_ 1024
#define M_ (B_*K_)      // 32768 rows
#define KW_ 5
#define EPS_ 1e-5f
#define NC_ 64
#define CL_ (K_/NC_)    // 32 per chunk

typedef __attribute__((ext_vector_type(8))) short short8;
typedef __attribute__((ext_vector_type(4))) float f32x4;
typedef __attribute__((ext_vector_type(8))) float f32x8;

typedef const __attribute__((address_space(1))) unsigned int* gas_u32;
typedef __attribute__((address_space(3))) unsigned int* las_u32;

static __device__ __forceinline__ float bf2f(unsigned short u) {
    unsigned int v = ((unsigned int)u) << 16;
    return __builtin_bit_cast(float, v);
}
static __device__ __forceinline__ unsigned short f2bf(float f) {
    unsigned int x = __builtin_bit_cast(unsigned int, f);
    unsigned int r = (x + 0x7FFFu + ((x >> 16) & 1u)) >> 16;
    return (unsigned short)r;
}
static __device__ __forceinline__ f32x8 cvt8(short8 v) {
    f32x8 f;
    #pragma unroll
    for (int j = 0; j < 8; ++j) f[j] = bf2f((unsigned short)v[j]);
    return f;
}

// ---------------- weight fp32 -> bf16 conversion ----------------
__global__ __launch_bounds__(256) void k_wconv(const float* __restrict__ Wa,
                                               const float* __restrict__ Wb,
                                               const float* __restrict__ Wout,
                                               unsigned short* __restrict__ Wcat,
                                               unsigned short* __restrict__ WoutB) {
    const int NW = INNER_ * D_;  // 524288
    int idx = blockIdx.x * 256 + threadIdx.x;
    if (idx < NW)            Wcat[idx]       = f2bf(Wa[idx]);
    else if (idx < 2 * NW)   Wcat[idx]       = f2bf(Wb[idx - NW]);
    else                     WoutB[idx-2*NW] = f2bf(Wout[idx - 2*NW]);
}

// ---------------- RMSNorm: one wave per row of 512 ----------------
__global__ __launch_bounds__(256) void k_rmsnorm(const float* __restrict__ x,
                                                 const float* __restrict__ w,
                                                 unsigned short* __restrict__ h) {
    int row  = blockIdx.x * 4 + (threadIdx.x >> 6);
    int lane = threadIdx.x & 63;
    const float4* xr = (const float4*)(x + (size_t)row * D_);
    float4 v0 = xr[lane];
    float4 v1 = xr[64 + lane];
    float ss = v0.x*v0.x + v0.y*v0.y + v0.z*v0.z + v0.w*v0.w
             + v1.x*v1.x + v1.y*v1.y + v1.z*v1.z + v1.w*v1.w;
    #pragma unroll
    for (int off = 32; off; off >>= 1) ss += __shfl_xor(ss, off, 64);
    float r = rsqrtf(ss * (1.0f / D_) + EPS_);
    const float4* wv = (const float4*)w;
    float4 w0 = wv[lane], w1 = wv[64 + lane];
    ushort4 o0, o1;
    o0.x = f2bf(v0.x * r * w0.x); o0.y = f2bf(v0.y * r * w0.y);
    o0.z = f2bf(v0.z * r * w0.z); o0.w = f2bf(v0.w * r * w0.w);
    o1.x = f2bf(v1.x * r * w1.x); o1.y = f2bf(v1.y * r * w1.y);
    o1.z = f2bf(v1.z * r * w1.z); o1.w = f2bf(v1.w * r * w1.w);
    ushort4* hr = (ushort4*)(h + (size_t)row * D_);
    hr[lane]      = o0;
    hr[64 + lane] = o1;
}

// ---------------- 256x256 bf16 MFMA GEMM, C = A * B^T, counted-vmcnt pipe ----
// 8 waves (2M x 4N), per-wave 128x64 out = acc[8][4]. BK=64, 2 LDS dbuf.
// XCD swizzle: contiguous swz chunk per XCD, N-FASTEST within chunk so each
// XCD's A working set (~2MB for 32 resident blocks) stays L2-resident.
template<int EPI>
__global__ __launch_bounds__(512) void k_gemm256(
    const unsigned short* __restrict__ A,
    const unsigned short* __restrict__ Bw,
    void* __restrict__ Cv,
    const float* __restrict__ Xadd,
    int Kd, int Nld)
{
    __shared__ __align__(16) unsigned short lA[2][256 * 64];
    __shared__ __align__(16) unsigned short lB[2][256 * 64];
    const int tid  = threadIdx.x;
    const int w    = tid >> 6, lane = tid & 63;
    const int wr   = w >> 2,   wc   = w & 3;

    // XCD-aware bijective swizzle (nwg % 8 == 0 here); n fastest within chunk
    const int nwg = gridDim.x * gridDim.y;
    const int fid = blockIdx.y * gridDim.x + blockIdx.x;
    const int swz = (fid & 7) * (nwg >> 3) + (fid >> 3);
    const int m0  = (swz / gridDim.y) * 256;
    const int n0  = (swz % gridDim.y) * 256;

    // staging map: per chunk j (64 rows), wave w fills rows [j*64+w*8, +8)
    const int srow = w * 8 + (lane >> 3);             // + j*64 per chunk
    const int scol = ((lane & 7) ^ (lane >> 3)) << 3; // pre-swizzled source col
    const int NT   = Kd >> 6;

    auto stage = [&](int t, int buf) {
        const int kt = t << 6;
        const unsigned short* ga = A  + (size_t)(m0 + srow) * Kd + kt + scol;
        const unsigned short* gb = Bw + (size_t)(n0 + srow) * Kd + kt + scol;
        #pragma unroll
        for (int j = 0; j < 4; ++j) {
            __builtin_amdgcn_global_load_lds((gas_u32)(ga + (size_t)j * 64 * Kd),
                                             (las_u32)(&lA[buf][(j * 64 + w * 8) * 64]), 16, 0, 0);
            __builtin_amdgcn_global_load_lds((gas_u32)(gb + (size_t)j * 64 * Kd),
                                             (las_u32)(&lB[buf][(j * 64 + w * 8) * 64]), 16, 0, 0);
        }
    };

    f32x4 acc[8][4];
    #pragma unroll
    for (int m = 0; m < 8; ++m)
        #pragma unroll
        for (int n = 0; n < 4; ++n) acc[m][n] = (f32x4){0.f, 0.f, 0.f, 0.f};

    const int lrow = lane & 15;
    const int hb   = (lane >> 4) << 4;   // 16B slot within 128B row
    const int xr   = (lrow & 7) << 4;    // read-side swizzle

    stage(0, 0);
    stage(1, 1);

    for (int t = 0; t < NT; ++t) {
        const int buf = t & 1;
        if (t + 1 < NT) asm volatile("s_waitcnt vmcnt(8)" ::: "memory");
        else            asm volatile("s_waitcnt vmcnt(0)" ::: "memory");
        __builtin_amdgcn_s_barrier();

        const char* pa = (const char*)lA[buf];
        const char* pb = (const char*)lB[buf];

        short8 a0[8], b0[4];
        #pragma unroll
        for (int m = 0; m < 8; ++m)
            a0[m] = *(const short8*)(pa + (wr*128 + m*16 + lrow) * 128 + (hb ^ xr));
        #pragma unroll
        for (int n = 0; n < 4; ++n)
            b0[n] = *(const short8*)(pb + (wc*64 + n*16 + lrow) * 128 + (hb ^ xr));

        __builtin_amdgcn_s_setprio(1);
        #pragma unroll
        for (int m = 0; m < 8; ++m)
            #pragma unroll
            for (int n = 0; n < 4; ++n)
                acc[m][n] = __builtin_amdgcn_mfma_f32_16x16x32_bf16(a0[m], b0[n], acc[m][n], 0, 0, 0);
        __builtin_amdgcn_s_setprio(0);

        short8 a1[8], b1[4];
        #pragma unroll
        for (int m = 0; m < 8; ++m)
            a1[m] = *(const short8*)(pa + (wr*128 + m*16 + lrow) * 128 + ((64 + hb) ^ xr));
        #pragma unroll
        for (int n = 0; n < 4; ++n)
            b1[n] = *(const short8*)(pb + (wc*64 + n*16 + lrow) * 128 + ((64 + hb) ^ xr));

        asm volatile("s_waitcnt lgkmcnt(0)" ::: "memory");   // all reads of buf done
        __builtin_amdgcn_s_barrier();                        // ...across all waves
        if (t + 2 < NT) stage(t + 2, buf);                   // refill while MFMA runs

        __builtin_amdgcn_s_setprio(1);
        #pragma unroll
        for (int m = 0; m < 8; ++m)
            #pragma unroll
            for (int n = 0; n < 4; ++n)
                acc[m][n] = __builtin_amdgcn_mfma_f32_16x16x32_bf16(a1[m], b1[n], acc[m][n], 0, 0, 0);
        __builtin_amdgcn_s_setprio(0);
    }

    // epilogue: D layout col = lane&15, row = (lane>>4)*4 + r
    #pragma unroll
    for (int m = 0; m < 8; ++m) {
        int mrow = m0 + wr*128 + m*16 + ((lane >> 4) << 2);
        #pragma unroll
        for (int n = 0; n < 4; ++n) {
            int ncol = n0 + wc*64 + n*16 + (lane & 15);
            f32x4 v = acc[m][n];
            #pragma unroll
            for (int r = 0; r < 4; ++r) {
                size_t off = (size_t)(mrow + r) * Nld + ncol;
                if (EPI == 0) ((unsigned short*)Cv)[off] = f2bf(v[r]);
                else          ((float*)Cv)[off] = Xadd[off] + v[r];
            }
        }
    }
}

// ---------------- prefix: per (b,channel), chain chunk-end states ----------
__global__ __launch_bounds__(256) void k_prefix(const float* __restrict__ alpha,
                                                const float* __restrict__ sEnd,
                                                float* __restrict__ sPre) {
    int idx = blockIdx.x * 256 + threadIdx.x;   // 0..16383
    int b = idx >> 10, i = idx & 1023;
    float Aa = 1.f / (1.f + __expf(-alpha[i]));
    float Ap = Aa;
    #pragma unroll
    for (int t = 0; t < 5; ++t) Ap = Ap * Ap;   // Aa^32 (CL=32)
    float s = 0.f;
    for (int c = 0; c < NC_; ++c) {
        size_t off = ((size_t)(b * NC_ + c)) * INNER_ + i;
        sPre[off] = s;
        s = s * Ap + sEnd[off];
    }
}

// ---------------- conv5 + SiLU + chunked selective scan (vectorized x8) -----
template<int PASS>
__global__ __launch_bounds__(256) void k_scan(
    const unsigned short* __restrict__ ab,
    const float* __restrict__ conv_w, const float* __restrict__ conv_b,
    const float* __restrict__ alpha,  const float* __restrict__ beta,
    const float* __restrict__ gamma,  const float* __restrict__ delta,
    float* __restrict__ sEnd, const float* __restrict__ sPre,
    unsigned short* __restrict__ g)
{
    const int tid = threadIdx.x;
    const int c   = blockIdx.x * 2 + (tid >> 7);   // chunk 0..63 (wave-uniform)
    const int b   = blockIdx.y;
    const int ch  = (tid & 127) * 8;               // channel base 0..1016

    f32x8 w0, w1, w2, w3, w4, bias, Aa, bet, gam, del;
    #pragma unroll
    for (int j = 0; j < 8; ++j) {
        int i = ch + j;
        w0[j] = conv_w[i*KW_+0]; w1[j] = conv_w[i*KW_+1]; w2[j] = conv_w[i*KW_+2];
        w3[j] = conv_w[i*KW_+3]; w4[j] = conv_w[i*KW_+4];
        bias[j] = conv_b[i];
        Aa[j]  = 1.f / (1.f + __expf(-alpha[i]));
        bet[j] = beta[i];
        if (PASS == 1) { gam[j] = gamma[i]; del[j] = delta[i]; }
    }

    const int k0 = c * CL_;
    const size_t rowbase = (size_t)b * K_;

    #define LDV(k) (((unsigned)(k) < (unsigned)K_) \
        ? cvt8(*(const short8*)(ab + (rowbase + (k)) * 2048 + ch)) \
        : (f32x8){0.f,0.f,0.f,0.f,0.f,0.f,0.f,0.f})

    f32x8 am2 = LDV(k0 - 2), am1 = LDV(k0 - 1), a0v = LDV(k0), ap1 = LDV(k0 + 1);

    f32x8 s;
    if (PASS == 1) {
        s = *(const f32x8*)(sPre + ((size_t)(b * NC_ + c)) * INNER_ + ch);
    } else {
        #pragma unroll
        for (int j = 0; j < 8; ++j) s[j] = 0.f;
    }

    #pragma unroll 2
    for (int kk = 0; kk < CL_; ++kk) {
        int k = k0 + kk;
        f32x8 ap2 = LDV(k + 2);
        f32x8 v = w0*am2 + w1*am1 + w2*a0v + w3*ap1 + w4*ap2 + bias;
        f32x8 u;
        #pragma unroll
        for (int j = 0; j < 8; ++j) u[j] = v[j] / (1.f + __expf(-v[j]));
        s = Aa * s + bet * u;
        if (PASS == 1) {
            f32x8 bv = cvt8(*(const short8*)(ab + (rowbase + k) * 2048 + INNER_ + ch));
            f32x8 gv = (gam * s + del * u) * bv;
            short8 o;
            #pragma unroll
            for (int j = 0; j < 8; ++j) o[j] = (short)f2bf(gv[j]);
            *(short8*)(g + (rowbase + k) * INNER_ + ch) = o;
        }
        am2 = am1; am1 = a0v; a0v = ap1; ap1 = ap2;
    }
    if (PASS == 0)
        *(f32x8*)(sEnd + ((size_t)(b * NC_ + c)) * INNER_ + ch) = s;
    #undef LDV
}

// ---------------- launch ----------------
extern "C" void kernel_launch(void* const* d_in, const int* in_sizes, int n_in,
                              void* d_out, int out_size, void* d_ws, size_t ws_size,
                              hipStream_t stream) {
    const float* x      = (const float*)d_in[0];
    const float* norm_w = (const float*)d_in[1];
    const float* Wa     = (const float*)d_in[2];
    const float* Wb     = (const float*)d_in[3];
    const float* conv_w = (const float*)d_in[4];
    const float* conv_b = (const float*)d_in[5];
    const float* alpha  = (const float*)d_in[6];
    const float* beta   = (const float*)d_in[7];
    const float* gamma  = (const float*)d_in[8];
    const float* delta  = (const float*)d_in[9];
    const float* Wout   = (const float*)d_in[10];
    float* out = (float*)d_out;

    char* ws = (char*)d_ws;
    unsigned short* h    = (unsigned short*)ws; ws += (size_t)M_ * D_ * 2;        // 32 MB
    unsigned short* Wcat = (unsigned short*)ws; ws += (size_t)2048 * 512 * 2;     // 2 MB
    unsigned short* WoB  = (unsigned short*)ws; ws += (size_t)512 * 1024 * 2;     // 1 MB
    unsigned short* abb  = (unsigned short*)ws; ws += (size_t)M_ * 2048 * 2;      // 128 MB
    unsigned short* g    = (unsigned short*)ws; ws += (size_t)M_ * 1024 * 2;      // 64 MB
    float* sEnd          = (float*)ws;          ws += (size_t)B_ * NC_ * INNER_ * 4; // 4 MB
    float* sPre          = (float*)ws;          ws += (size_t)B_ * NC_ * INNER_ * 4; // 4 MB

    k_wconv  <<<6144, 256, 0, stream>>>(Wa, Wb, Wout, Wcat, WoB);
    k_rmsnorm<<<M_ / 4, 256, 0, stream>>>(x, norm_w, h);
    // a|b = h @ [Wa;Wb]^T : M=32768, K=512, N=2048
    k_gemm256<0><<<dim3(M_ / 256, 2048 / 256), 512, 0, stream>>>(h, Wcat, abb, nullptr, 512, 2048);
    // chunked scan: pass0 (chunk ends) -> prefix chain -> pass1 (emit g)
    k_scan<0><<<dim3(NC_ / 2, B_), 256, 0, stream>>>(abb, conv_w, conv_b, alpha, beta, gamma, delta, sEnd, nullptr, g);
    k_prefix<<<64, 256, 0, stream>>>(alpha, sEnd, sPre);
    k_scan<1><<<dim3(NC_ / 2, B_), 256, 0, stream>>>(abb, conv_w, conv_b, alpha, beta, gamma, delta, sEnd, sPre, g);
    // out = x + g @ Wout^T : M=32768, K=1024, N=512
    k_gemm256<1><<<dim3(M_ / 256, 512 / 256), 512, 0, stream>>>(g, WoB, out, x, 1024, 512);
}